// Round 2
// baseline (379.308 us; speedup 1.0000x reference)
//
#include <hip/hip_runtime.h>
#include <hip/hip_bf16.h>
#include <hip/hip_fp16.h>
#include <stdint.h>

#define N_NODES 50000
#define E_EDGES 800000

typedef short s16x8 __attribute__((ext_vector_type(8)));
typedef float f32x4 __attribute__((ext_vector_type(4)));

__device__ __forceinline__ float bf2f(unsigned int u) {
    return __uint_as_float(u << 16);
}
__device__ __forceinline__ unsigned short f2bf(float f) {
    unsigned int u = __float_as_uint(f);
    unsigned int r = (u + 0x7FFFu + ((u >> 16) & 1u)) >> 16;
    return (unsigned short)r;
}
__device__ __forceinline__ unsigned short f2h_bits(float f) {
    return __half_as_ushort(__float2half(f));
}
__device__ __forceinline__ float2 h2f2(unsigned int u) {
    __half2 h = *reinterpret_cast<const __half2*>(&u);
    return __half22float2(h);
}

// ---------------- CSR construction + fused x->fp16 convert ----------------
// E_EDGES == N_NODES*128/8, so each thread histograms one edge AND converts
// 8 floats of x to fp16.

__global__ void hist_conv(const int* __restrict__ dst, int* __restrict__ deg,
                          const float* __restrict__ x,
                          unsigned short* __restrict__ xh) {
    int e = blockIdx.x * blockDim.x + threadIdx.x;
    if (e >= E_EDGES) return;
    atomicAdd(&deg[dst[e]], 1);
    const float4* xv = (const float4*)x;
    float4 a = xv[(size_t)2 * e];
    float4 b = xv[(size_t)2 * e + 1];
    s16x8 h;
    h[0] = (short)f2h_bits(a.x); h[1] = (short)f2h_bits(a.y);
    h[2] = (short)f2h_bits(a.z); h[3] = (short)f2h_bits(a.w);
    h[4] = (short)f2h_bits(b.x); h[5] = (short)f2h_bits(b.y);
    h[6] = (short)f2h_bits(b.z); h[7] = (short)f2h_bits(b.w);
    *(s16x8*)(xh + (size_t)e * 8) = h;
}

__global__ __launch_bounds__(1024) void scan1(const int* __restrict__ deg,
                                              int* __restrict__ lexcl,
                                              int* __restrict__ btot) {
    __shared__ int wsum[16];
    int gid = blockIdx.x * 1024 + threadIdx.x;
    int lane = threadIdx.x & 63, wid = threadIdx.x >> 6;
    int v = (gid < N_NODES) ? deg[gid] : 0;
    int x = v;
#pragma unroll
    for (int off = 1; off < 64; off <<= 1) {
        int t = __shfl_up(x, off);
        if (lane >= off) x += t;
    }
    if (lane == 63) wsum[wid] = x;
    __syncthreads();
    if (wid == 0 && lane < 16) {
        int w = wsum[lane];
#pragma unroll
        for (int off = 1; off < 16; off <<= 1) {
            int t = __shfl_up(w, off);
            if (lane >= off) w += t;
        }
        wsum[lane] = w;
    }
    __syncthreads();
    int excl = x - v + (wid ? wsum[wid - 1] : 0);
    if (gid < N_NODES) lexcl[gid] = excl;
    if (threadIdx.x == 0) btot[blockIdx.x] = wsum[15];
}

__global__ void scan2(const int* __restrict__ btot, int* __restrict__ bbase,
                      int nb) {
    int lane = threadIdx.x;
    int v = (lane < nb) ? btot[lane] : 0;
    int x = v;
#pragma unroll
    for (int off = 1; off < 64; off <<= 1) {
        int t = __shfl_up(x, off);
        if (lane >= off) x += t;
    }
    if (lane < nb) bbase[lane] = x - v;
}

__global__ void scan3(const int* __restrict__ lexcl, const int* __restrict__ bbase,
                      int* __restrict__ rowptr, int* __restrict__ cursor) {
    int gid = blockIdx.x * blockDim.x + threadIdx.x;
    if (gid < N_NODES) {
        int r = lexcl[gid] + bbase[gid >> 10];
        rowptr[gid] = r;
        cursor[gid] = r;
    }
    if (gid == 0) rowptr[N_NODES] = E_EDGES;
}

__global__ void fill_csr(const int* __restrict__ src, const int* __restrict__ dst,
                         int* __restrict__ cursor, unsigned short* __restrict__ perm) {
    int e = blockIdx.x * blockDim.x + threadIdx.x;
    if (e >= E_EDGES) return;
    int d = dst[e];
    int pos = atomicAdd(&cursor[d], 1);
    perm[pos] = (unsigned short)src[e];
}

// ---------------- Aggregation over fp16 rows -----------
// feat: [N,128] fp16. acc in f32. out: [N,128] f32.
__global__ __launch_bounds__(256) void gather_agg_h(
    const unsigned short* __restrict__ feat,
    const int* __restrict__ rowptr,
    const unsigned short* __restrict__ perm,
    float* __restrict__ out) {
    int node = (blockIdx.x * 256 + threadIdx.x) >> 6;
    if (node >= N_NODES) return;
    int lane = threadIdx.x & 63;
    const unsigned int* fv = (const unsigned int*)feat;  // 64 uints (=128 fp16) per row
    float2 acc = h2f2(fv[(size_t)node * 64 + lane]);     // self term
    int beg = rowptr[node], end = rowptr[node + 1];
    for (int base = beg; base < end; base += 64) {
        int cnt = end - base; if (cnt > 64) cnt = 64;
        int pv = (base + lane < end) ? (int)perm[base + lane] : 0;
        int j = 0;
        for (; j + 3 < cnt; j += 4) {
            int s0 = __shfl(pv, j);
            int s1 = __shfl(pv, j + 1);
            int s2 = __shfl(pv, j + 2);
            int s3 = __shfl(pv, j + 3);
            unsigned int u0 = fv[(size_t)s0 * 64 + lane];
            unsigned int u1 = fv[(size_t)s1 * 64 + lane];
            unsigned int u2 = fv[(size_t)s2 * 64 + lane];
            unsigned int u3 = fv[(size_t)s3 * 64 + lane];
            float2 f0 = h2f2(u0), f1 = h2f2(u1), f2 = h2f2(u2), f3 = h2f2(u3);
            acc.x += (f0.x + f1.x) + (f2.x + f3.x);
            acc.y += (f0.y + f1.y) + (f2.y + f3.y);
        }
        for (; j < cnt; j++) {
            int s = __shfl(pv, j);
            float2 f = h2f2(fv[(size_t)s * 64 + lane]);
            acc.x += f.x;
            acc.y += f.y;
        }
    }
    ((float2*)out)[(size_t)node * 64 + lane] = acc;
}

// ---- Weight pre-split (fused) ----
__device__ __forceinline__ void prep_one(const float* __restrict__ W,
                                         unsigned short* __restrict__ Whi,
                                         unsigned short* __restrict__ Wlo,
                                         int K, int F, int Fpad, int i) {
    int S = K / 32, T = Fpad / 16;
    int total = T * S * 64;
    if (i >= total) return;
    int lane = i & 63;
    int s = (i >> 6) % S;
    int t = (i >> 6) / S;
    int col = t * 16 + (lane & 15);
    int k0 = s * 32 + (lane >> 4) * 8;
    s16x8 vh, vl;
#pragma unroll
    for (int j = 0; j < 8; j++) {
        float w = (col < F) ? W[(size_t)(k0 + j) * F + col] : 0.f;
        unsigned short h = f2bf(w);
        float r = w - bf2f(h);
        vh[j] = (short)h;
        vl[j] = (short)f2bf(r);
    }
    *(s16x8*)(Whi + (size_t)i * 8) = vh;
    *(s16x8*)(Wlo + (size_t)i * 8) = vl;
}

__global__ void prep_all(const float* W1, const float* W2, const float* W3,
                         const float* W4, const float* Wl,
                         unsigned short* W1h, unsigned short* W1l,
                         unsigned short* W2h, unsigned short* W2l,
                         unsigned short* W3h, unsigned short* W3l,
                         unsigned short* W4h, unsigned short* W4l,
                         unsigned short* Wlh, unsigned short* Wll) {
    int b = blockIdx.x, t = threadIdx.x;
    if (b < 8)       prep_one(W1, W1h, W1l, 128, 128, 128, b * 256 + t);
    else if (b < 16) prep_one(W2, W2h, W2l, 128, 128, 128, (b - 8) * 256 + t);
    else if (b < 32) prep_one(W3, W3h, W3l, 128, 256, 256, (b - 16) * 256 + t);
    else if (b < 64) prep_one(W4, W4h, W4l, 256, 256, 256, (b - 32) * 256 + t);
    else             prep_one(Wl, Wlh, Wll, 256, 40, 64, (b - 64) * 256 + t);
}

// ---- GEMM, split-precision bf16 MFMA.
// Column split is across WAVES of one block (all 4 waves share the same
// 16*RPW-row A panel -> A fetched from HBM once per panel, same XCD by
// construction). Numerically identical to the previous block-CSPLIT form.
// HOUT: write output as fp16 (for the buffer feeding the next aggregation).
template <int K, int F, int FOUT, bool RELU, int RPW, bool HOUT>
__global__ __launch_bounds__(256) void gemm_split(
    const float* __restrict__ A,
    const unsigned short* __restrict__ Whi,
    const unsigned short* __restrict__ Wlo,
    const float* __restrict__ bias,
    float* __restrict__ out) {
    constexpr int S = K / 32;
    constexpr int T = F / 16;
    constexpr int TL = T / 4;            // per-wave column tiles (4 waves/block)
    int wave = threadIdx.x >> 6;
    int lane = threadIdx.x & 63;
    int row0 = blockIdx.x * (16 * RPW);
    if (row0 >= N_NODES) return;
    int lm = lane & 15;
    int quad = lane >> 4;
    bool rv[RPW];
#pragma unroll
    for (int r = 0; r < RPW; r++) rv[r] = (row0 + r * 16) < N_NODES;

    f32x4 acc[TL][RPW];
#pragma unroll
    for (int t = 0; t < TL; t++)
#pragma unroll
        for (int r = 0; r < RPW; r++) {
            f32x4 z = {0.f, 0.f, 0.f, 0.f};
            acc[t][r] = z;
        }

#pragma unroll
    for (int s = 0; s < S; s++) {
        s16x8 ah[RPW], al[RPW];
#pragma unroll
        for (int r = 0; r < RPW; r++) {
            int rr = rv[r] ? row0 + r * 16 : row0;
            const float* ap = A + (size_t)(rr + lm) * K + s * 32 + quad * 8;
            float4 x0 = *(const float4*)ap;
            float4 x1 = *(const float4*)(ap + 4);
            float v[8] = {x0.x, x0.y, x0.z, x0.w, x1.x, x1.y, x1.z, x1.w};
#pragma unroll
            for (int j = 0; j < 8; j++) {
                unsigned short h = f2bf(v[j]);
                float res = v[j] - bf2f(h);
                ah[r][j] = (short)h;
                al[r][j] = (short)f2bf(res);
            }
        }
#pragma unroll
        for (int t = 0; t < TL; t++) {
            int tg = wave * TL + t;
            const size_t fi = (size_t)((tg * S + s) * 64 + lane) * 8;
            const s16x8 bh = *(const s16x8*)(Whi + fi);
            const s16x8 bl = *(const s16x8*)(Wlo + fi);
#pragma unroll
            for (int r = 0; r < RPW; r++) {
                acc[t][r] = __builtin_amdgcn_mfma_f32_16x16x32_bf16(ah[r], bh, acc[t][r], 0, 0, 0);
                acc[t][r] = __builtin_amdgcn_mfma_f32_16x16x32_bf16(al[r], bh, acc[t][r], 0, 0, 0);
                acc[t][r] = __builtin_amdgcn_mfma_f32_16x16x32_bf16(ah[r], bl, acc[t][r], 0, 0, 0);
            }
        }
    }

#pragma unroll
    for (int r = 0; r < RPW; r++) {
        if (!rv[r]) break;
        int orow = row0 + r * 16 + quad * 4;
#pragma unroll
        for (int t = 0; t < TL; t++) {
            int col = (wave * TL + t) * 16 + lm;
            if (FOUT < F && col >= FOUT) continue;
            float bv = bias[col];
#pragma unroll
            for (int q = 0; q < 4; q++) {
                float vv = acc[t][r][q] + bv;
                if (RELU) vv = fmaxf(vv, 0.f);
                if (HOUT) {
                    ((unsigned short*)out)[(size_t)(orow + q) * FOUT + col] = f2h_bits(vv);
                } else {
                    out[(size_t)(orow + q) * FOUT + col] = vv;
                }
            }
        }
    }
}

extern "C" void kernel_launch(void* const* d_in, const int* in_sizes, int n_in,
                              void* d_out, int out_size, void* d_ws, size_t ws_size,
                              hipStream_t stream) {
    const float* x  = (const float*)d_in[0];
    const int* ei   = (const int*)d_in[1];
    const float* W1 = (const float*)d_in[2];
    const float* b1 = (const float*)d_in[3];
    const float* W2 = (const float*)d_in[4];
    const float* b2 = (const float*)d_in[5];
    const float* W3 = (const float*)d_in[6];
    const float* b3 = (const float*)d_in[7];
    const float* W4 = (const float*)d_in[8];
    const float* b4 = (const float*)d_in[9];
    const float* Wl = (const float*)d_in[10];
    const float* bl = (const float*)d_in[11];
    float* out = (float*)d_out;

    const int* src = ei;
    const int* dst = ei + E_EDGES;

    char* ws = (char*)d_ws;
    const size_t R = (size_t)N_NODES * 256 * 4;        // 51.2e6 B
    float* R1 = (float*)ws;
    float* R2 = (float*)(ws + R);
    float* hF  = R1;                          // [N,128] agg (layer 1 & 2)
    float* h1  = R2;                          // [N,128]
    // fp16 plane: reused for x(fp16) then h1b(fp16). Lives in old h1b slot.
    unsigned short* xh = (unsigned short*)(ws + R + (size_t)N_NODES * 128 * 4);
    float* hF2 = R1;
    float* h2  = R2;                          // [N,256]
    float* h2b = R1;                          // [N,256]
    size_t off = 2 * R;
    unsigned short* W1h = (unsigned short*)(ws + off); off += 16384 * 2;
    unsigned short* W1l = (unsigned short*)(ws + off); off += 16384 * 2;
    unsigned short* W2h = (unsigned short*)(ws + off); off += 16384 * 2;
    unsigned short* W2l = (unsigned short*)(ws + off); off += 16384 * 2;
    unsigned short* W3h = (unsigned short*)(ws + off); off += 32768 * 2;
    unsigned short* W3l = (unsigned short*)(ws + off); off += 32768 * 2;
    unsigned short* W4h = (unsigned short*)(ws + off); off += 65536 * 2;
    unsigned short* W4l = (unsigned short*)(ws + off); off += 65536 * 2;
    unsigned short* Wlh = (unsigned short*)(ws + off); off += 16384 * 2;   // 256x64 padded
    unsigned short* Wll = (unsigned short*)(ws + off); off += 16384 * 2;
    off = (off + 255) & ~(size_t)255;
    int* deg    = (int*)(ws + off); off += (size_t)(N_NODES + 1) * 4;
    int* cursor = (int*)(ws + off); off += (size_t)(N_NODES + 1) * 4;
    int* rowptr = (int*)(ws + off); off += (size_t)(N_NODES + 1) * 4;
    unsigned short* perm = (unsigned short*)(ws + off); off += (size_t)E_EDGES * 2;
    off = (off + 255) & ~(size_t)255;
    int* lexcl  = (int*)(ws + off); off += (size_t)N_NODES * 4;
    int* btot   = (int*)(ws + off); off += 64 * 4;
    int* bbase  = (int*)(ws + off); off += 64 * 4;
    (void)ws_size; (void)in_sizes; (void)n_in; (void)out_size;

    const int NB = (N_NODES + 1023) / 1024;

    // ---- CSR build + x->fp16 convert (fused: E == N*128/8 threads) ----
    (void)hipMemsetAsync(deg, 0, (size_t)(N_NODES + 1) * 4, stream);
    hist_conv<<<(E_EDGES + 255) / 256, 256, 0, stream>>>(dst, deg, x, xh);
    scan1<<<NB, 1024, 0, stream>>>(deg, lexcl, btot);
    scan2<<<1, 64, 0, stream>>>(btot, bbase, NB);
    scan3<<<(N_NODES + 255) / 256, 256, 0, stream>>>(lexcl, bbase, rowptr, cursor);
    fill_csr<<<(E_EDGES + 255) / 256, 256, 0, stream>>>(src, dst, cursor, perm);

    // ---- Weight pre-split (Wl padded to 64 cols -> 8 blocks) ----
    prep_all<<<72, 256, 0, stream>>>(W1, W2, W3, W4, Wl,
                                     W1h, W1l, W2h, W2l, W3h, W3l,
                                     W4h, W4l, Wlh, Wll);

    const int aggBlocks = (N_NODES * 64 + 255) / 256;   // one wave per node
    const int rblk = (N_NODES + 31) / 32;               // 1563 blocks, 32 rows each

    // ---- Layer 1 ----
    gather_agg_h<<<aggBlocks, 256, 0, stream>>>(xh, rowptr, perm, hF);
    gemm_split<128, 128, 128, true, 2, false><<<rblk, 256, 0, stream>>>(hF, W1h, W1l, b1, h1);
    // GEMM2 writes h1b directly as fp16 into xh (its only consumer is the gather)
    gemm_split<128, 128, 128, true, 2, true><<<rblk, 256, 0, stream>>>(h1, W2h, W2l, b2, (float*)xh);

    // ---- Layer 2 ----
    gather_agg_h<<<aggBlocks, 256, 0, stream>>>(xh, rowptr, perm, hF2);
    gemm_split<128, 256, 256, true, 2, false><<<rblk, 256, 0, stream>>>(hF2, W3h, W3l, b3, h2);
    gemm_split<256, 256, 256, true, 2, false><<<rblk, 256, 0, stream>>>(h2, W4h, W4l, b4, h2b);

    // ---- Final linear (padded to F=64, 4 waves x 1 tile) ----
    gemm_split<256, 64, 40, false, 2, false><<<rblk, 256, 0, stream>>>(h2b, Wlh, Wll, bl, out);
}

// Round 3
// 339.593 us; speedup vs baseline: 1.1169x; 1.1169x over previous
//
#include <hip/hip_runtime.h>
#include <hip/hip_bf16.h>
#include <hip/hip_fp16.h>
#include <stdint.h>

#define N_NODES 50000
#define E_EDGES 800000

typedef short s16x8 __attribute__((ext_vector_type(8)));
typedef _Float16 f16x8 __attribute__((ext_vector_type(8)));
typedef float f32x4 __attribute__((ext_vector_type(4)));

__device__ __forceinline__ unsigned short f2h_bits(float f) {
    return __half_as_ushort(__float2half(f));
}
__device__ __forceinline__ float h2f(unsigned short u) {
    __half h = *reinterpret_cast<const __half*>(&u);
    return __half2float(h);
}
__device__ __forceinline__ float2 h2f2(unsigned int u) {
    __half2 h = *reinterpret_cast<const __half2*>(&u);
    return __half22float2(h);
}

// ---------------- CSR construction + fused x->fp16 convert ----------------
// E_EDGES == N_NODES*128/8, so each thread histograms one edge AND converts
// 8 floats of x to fp16.

__global__ void hist_conv(const int* __restrict__ dst, int* __restrict__ deg,
                          const float* __restrict__ x,
                          unsigned short* __restrict__ xh) {
    int e = blockIdx.x * blockDim.x + threadIdx.x;
    if (e >= E_EDGES) return;
    atomicAdd(&deg[dst[e]], 1);
    const float4* xv = (const float4*)x;
    float4 a = xv[(size_t)2 * e];
    float4 b = xv[(size_t)2 * e + 1];
    s16x8 h;
    h[0] = (short)f2h_bits(a.x); h[1] = (short)f2h_bits(a.y);
    h[2] = (short)f2h_bits(a.z); h[3] = (short)f2h_bits(a.w);
    h[4] = (short)f2h_bits(b.x); h[5] = (short)f2h_bits(b.y);
    h[6] = (short)f2h_bits(b.z); h[7] = (short)f2h_bits(b.w);
    *(s16x8*)(xh + (size_t)e * 8) = h;
}

__global__ __launch_bounds__(1024) void scan1(const int* __restrict__ deg,
                                              int* __restrict__ lexcl,
                                              int* __restrict__ btot) {
    __shared__ int wsum[16];
    int gid = blockIdx.x * 1024 + threadIdx.x;
    int lane = threadIdx.x & 63, wid = threadIdx.x >> 6;
    int v = (gid < N_NODES) ? deg[gid] : 0;
    int x = v;
#pragma unroll
    for (int off = 1; off < 64; off <<= 1) {
        int t = __shfl_up(x, off);
        if (lane >= off) x += t;
    }
    if (lane == 63) wsum[wid] = x;
    __syncthreads();
    if (wid == 0 && lane < 16) {
        int w = wsum[lane];
#pragma unroll
        for (int off = 1; off < 16; off <<= 1) {
            int t = __shfl_up(w, off);
            if (lane >= off) w += t;
        }
        wsum[lane] = w;
    }
    __syncthreads();
    int excl = x - v + (wid ? wsum[wid - 1] : 0);
    if (gid < N_NODES) lexcl[gid] = excl;
    if (threadIdx.x == 0) btot[blockIdx.x] = wsum[15];
}

__global__ void scan2(const int* __restrict__ btot, int* __restrict__ bbase,
                      int nb) {
    int lane = threadIdx.x;
    int v = (lane < nb) ? btot[lane] : 0;
    int x = v;
#pragma unroll
    for (int off = 1; off < 64; off <<= 1) {
        int t = __shfl_up(x, off);
        if (lane >= off) x += t;
    }
    if (lane < nb) bbase[lane] = x - v;
}

__global__ void scan3(const int* __restrict__ lexcl, const int* __restrict__ bbase,
                      int* __restrict__ rowptr, int* __restrict__ cursor) {
    int gid = blockIdx.x * blockDim.x + threadIdx.x;
    if (gid < N_NODES) {
        int r = lexcl[gid] + bbase[gid >> 10];
        rowptr[gid] = r;
        cursor[gid] = r;
    }
    if (gid == 0) rowptr[N_NODES] = E_EDGES;
}

__global__ void fill_csr(const int* __restrict__ src, const int* __restrict__ dst,
                         int* __restrict__ cursor, unsigned short* __restrict__ perm) {
    int e = blockIdx.x * blockDim.x + threadIdx.x;
    if (e >= E_EDGES) return;
    int d = dst[e];
    int pos = atomicAdd(&cursor[d], 1);
    perm[pos] = (unsigned short)src[e];
}

// ---------------- Aggregation over fp16 rows, fp16 output -----------
// feat: [N,128] fp16. acc in f32. out: [N,128] fp16.
__global__ __launch_bounds__(256) void gather_agg_h(
    const unsigned short* __restrict__ feat,
    const int* __restrict__ rowptr,
    const unsigned short* __restrict__ perm,
    unsigned short* __restrict__ out) {
    int node = (blockIdx.x * 256 + threadIdx.x) >> 6;
    if (node >= N_NODES) return;
    int lane = threadIdx.x & 63;
    const unsigned int* fv = (const unsigned int*)feat;  // 64 uints (=128 fp16) per row
    float2 acc = h2f2(fv[(size_t)node * 64 + lane]);     // self term
    int beg = rowptr[node], end = rowptr[node + 1];
    for (int base = beg; base < end; base += 64) {
        int cnt = end - base; if (cnt > 64) cnt = 64;
        int pv = (base + lane < end) ? (int)perm[base + lane] : 0;
        int j = 0;
        for (; j + 3 < cnt; j += 4) {
            int s0 = __shfl(pv, j);
            int s1 = __shfl(pv, j + 1);
            int s2 = __shfl(pv, j + 2);
            int s3 = __shfl(pv, j + 3);
            unsigned int u0 = fv[(size_t)s0 * 64 + lane];
            unsigned int u1 = fv[(size_t)s1 * 64 + lane];
            unsigned int u2 = fv[(size_t)s2 * 64 + lane];
            unsigned int u3 = fv[(size_t)s3 * 64 + lane];
            float2 f0 = h2f2(u0), f1 = h2f2(u1), f2 = h2f2(u2), f3 = h2f2(u3);
            acc.x += (f0.x + f1.x) + (f2.x + f3.x);
            acc.y += (f0.y + f1.y) + (f2.y + f3.y);
        }
        for (; j < cnt; j++) {
            int s = __shfl(pv, j);
            float2 f = h2f2(fv[(size_t)s * 64 + lane]);
            acc.x += f.x;
            acc.y += f.y;
        }
    }
    unsigned int o = (unsigned int)f2h_bits(acc.x) | ((unsigned int)f2h_bits(acc.y) << 16);
    ((unsigned int*)out)[(size_t)node * 64 + lane] = o;
}

// ---- Weight pre-split: fp16 hi + fp16 lo (residual scaled by 1024) ----
__device__ __forceinline__ void prep_one(const float* __restrict__ W,
                                         unsigned short* __restrict__ Whi,
                                         unsigned short* __restrict__ Wlo,
                                         int K, int F, int Fpad, int i) {
    int S = K / 32, T = Fpad / 16;
    int total = T * S * 64;
    if (i >= total) return;
    int lane = i & 63;
    int s = (i >> 6) % S;
    int t = (i >> 6) / S;
    int col = t * 16 + (lane & 15);
    int k0 = s * 32 + (lane >> 4) * 8;
    s16x8 vh, vl;
#pragma unroll
    for (int j = 0; j < 8; j++) {
        float w = (col < F) ? W[(size_t)(k0 + j) * F + col] : 0.f;
        unsigned short h = f2h_bits(w);
        float r = (w - h2f(h)) * 1024.0f;
        vh[j] = (short)h;
        vl[j] = (short)f2h_bits(r);
    }
    *(s16x8*)(Whi + (size_t)i * 8) = vh;
    *(s16x8*)(Wlo + (size_t)i * 8) = vl;
}

__global__ void prep_all(const float* W1, const float* W2, const float* W3,
                         const float* W4, const float* Wl,
                         unsigned short* W1h, unsigned short* W1l,
                         unsigned short* W2h, unsigned short* W2l,
                         unsigned short* W3h, unsigned short* W3l,
                         unsigned short* W4h, unsigned short* W4l,
                         unsigned short* Wlh, unsigned short* Wll) {
    int b = blockIdx.x, t = threadIdx.x;
    if (b < 8)       prep_one(W1, W1h, W1l, 128, 128, 128, b * 256 + t);
    else if (b < 16) prep_one(W2, W2h, W2l, 128, 128, 128, (b - 8) * 256 + t);
    else if (b < 32) prep_one(W3, W3h, W3l, 128, 256, 256, (b - 16) * 256 + t);
    else if (b < 64) prep_one(W4, W4h, W4l, 256, 256, 256, (b - 32) * 256 + t);
    else             prep_one(Wl, Wlh, Wll, 256, 40, 64, (b - 64) * 256 + t);
}

// ---- GEMM, fp16 MFMA. A is fp16 [N,K]; loads are the MFMA fragments
// directly (no conversion VALU, no dependent chains: all A loads issued
// up-front). Column split across the 4 waves of a block (A panel shared).
// W = Whi + Wlo/1024, two accumulator banks.
// HOUT: write output as fp16.
template <int K, int F, int FOUT, bool RELU, int RPW, bool HOUT>
__global__ __launch_bounds__(256) void gemm_h(
    const unsigned short* __restrict__ A,
    const unsigned short* __restrict__ Whi,
    const unsigned short* __restrict__ Wlo,
    const float* __restrict__ bias,
    float* __restrict__ out) {
    constexpr int S = K / 32;
    constexpr int T = F / 16;
    constexpr int TL = T / 4;            // per-wave column tiles (4 waves/block)
    int wave = threadIdx.x >> 6;
    int lane = threadIdx.x & 63;
    int row0 = blockIdx.x * (16 * RPW);
    if (row0 >= N_NODES) return;
    int lm = lane & 15;
    int quad = lane >> 4;
    bool rv[RPW];
#pragma unroll
    for (int r = 0; r < RPW; r++) rv[r] = (row0 + r * 16) < N_NODES;

    // Prefetch the whole A panel fragment-resident (independent loads).
    f16x8 a[RPW][S];
#pragma unroll
    for (int r = 0; r < RPW; r++) {
        int rr = rv[r] ? row0 + r * 16 : row0;
        const unsigned short* ap = A + (size_t)(rr + lm) * K + quad * 8;
#pragma unroll
        for (int s = 0; s < S; s++)
            a[r][s] = *(const f16x8*)(ap + s * 32);
    }

    f32x4 accH[TL][RPW], accL[TL][RPW];
#pragma unroll
    for (int t = 0; t < TL; t++)
#pragma unroll
        for (int r = 0; r < RPW; r++) {
            f32x4 z = {0.f, 0.f, 0.f, 0.f};
            accH[t][r] = z;
            accL[t][r] = z;
        }

#pragma unroll
    for (int s = 0; s < S; s++) {
#pragma unroll
        for (int t = 0; t < TL; t++) {
            int tg = wave * TL + t;
            const size_t fi = (size_t)((tg * S + s) * 64 + lane) * 8;
            const f16x8 bh = *(const f16x8*)(Whi + fi);
            const f16x8 bl = *(const f16x8*)(Wlo + fi);
#pragma unroll
            for (int r = 0; r < RPW; r++) {
                accH[t][r] = __builtin_amdgcn_mfma_f32_16x16x32_f16(a[r][s], bh, accH[t][r], 0, 0, 0);
                accL[t][r] = __builtin_amdgcn_mfma_f32_16x16x32_f16(a[r][s], bl, accL[t][r], 0, 0, 0);
            }
        }
    }

    const float ls = 1.0f / 1024.0f;
#pragma unroll
    for (int r = 0; r < RPW; r++) {
        if (!rv[r]) break;
        int orow = row0 + r * 16 + quad * 4;
#pragma unroll
        for (int t = 0; t < TL; t++) {
            int col = (wave * TL + t) * 16 + lm;
            if (FOUT < F && col >= FOUT) continue;
            float bv = bias[col];
#pragma unroll
            for (int q = 0; q < 4; q++) {
                float vv = fmaf(accL[t][r][q], ls, accH[t][r][q]) + bv;
                if (RELU) vv = fmaxf(vv, 0.f);
                if (HOUT) {
                    ((unsigned short*)out)[(size_t)(orow + q) * FOUT + col] = f2h_bits(vv);
                } else {
                    out[(size_t)(orow + q) * FOUT + col] = vv;
                }
            }
        }
    }
}

extern "C" void kernel_launch(void* const* d_in, const int* in_sizes, int n_in,
                              void* d_out, int out_size, void* d_ws, size_t ws_size,
                              hipStream_t stream) {
    const float* x  = (const float*)d_in[0];
    const int* ei   = (const int*)d_in[1];
    const float* W1 = (const float*)d_in[2];
    const float* b1 = (const float*)d_in[3];
    const float* W2 = (const float*)d_in[4];
    const float* b2 = (const float*)d_in[5];
    const float* W3 = (const float*)d_in[6];
    const float* b3 = (const float*)d_in[7];
    const float* W4 = (const float*)d_in[8];
    const float* b4 = (const float*)d_in[9];
    const float* Wl = (const float*)d_in[10];
    const float* bl = (const float*)d_in[11];
    float* out = (float*)d_out;

    const int* src = ei;
    const int* dst = ei + E_EDGES;

    char* ws = (char*)d_ws;
    size_t off = 0;
    // fp16 activation planes
    unsigned short* xh  = (unsigned short*)(ws + off); off += (size_t)N_NODES * 128 * 2; // x / h1b
    unsigned short* hFh = (unsigned short*)(ws + off); off += (size_t)N_NODES * 128 * 2; // agg out (both layers)
    unsigned short* h1h = (unsigned short*)(ws + off); off += (size_t)N_NODES * 128 * 2;
    unsigned short* h2h = (unsigned short*)(ws + off); off += (size_t)N_NODES * 256 * 2;
    unsigned short* h2bh= (unsigned short*)(ws + off); off += (size_t)N_NODES * 256 * 2;
    // weight planes (fp16 hi / fp16 lo*1024)
    unsigned short* W1h = (unsigned short*)(ws + off); off += 16384 * 2;
    unsigned short* W1l = (unsigned short*)(ws + off); off += 16384 * 2;
    unsigned short* W2h = (unsigned short*)(ws + off); off += 16384 * 2;
    unsigned short* W2l = (unsigned short*)(ws + off); off += 16384 * 2;
    unsigned short* W3h = (unsigned short*)(ws + off); off += 32768 * 2;
    unsigned short* W3l = (unsigned short*)(ws + off); off += 32768 * 2;
    unsigned short* W4h = (unsigned short*)(ws + off); off += 65536 * 2;
    unsigned short* W4l = (unsigned short*)(ws + off); off += 65536 * 2;
    unsigned short* Wlh = (unsigned short*)(ws + off); off += 16384 * 2;   // 256x64 padded
    unsigned short* Wll = (unsigned short*)(ws + off); off += 16384 * 2;
    off = (off + 255) & ~(size_t)255;
    int* deg    = (int*)(ws + off); off += (size_t)(N_NODES + 1) * 4;
    int* cursor = (int*)(ws + off); off += (size_t)(N_NODES + 1) * 4;
    int* rowptr = (int*)(ws + off); off += (size_t)(N_NODES + 1) * 4;
    unsigned short* perm = (unsigned short*)(ws + off); off += (size_t)E_EDGES * 2;
    off = (off + 255) & ~(size_t)255;
    int* lexcl  = (int*)(ws + off); off += (size_t)N_NODES * 4;
    int* btot   = (int*)(ws + off); off += 64 * 4;
    int* bbase  = (int*)(ws + off); off += 64 * 4;
    (void)ws_size; (void)in_sizes; (void)n_in; (void)out_size;

    const int NB = (N_NODES + 1023) / 1024;

    // ---- CSR build + x->fp16 convert (fused: E == N*128/8 threads) ----
    (void)hipMemsetAsync(deg, 0, (size_t)(N_NODES + 1) * 4, stream);
    hist_conv<<<(E_EDGES + 255) / 256, 256, 0, stream>>>(dst, deg, x, xh);
    scan1<<<NB, 1024, 0, stream>>>(deg, lexcl, btot);
    scan2<<<1, 64, 0, stream>>>(btot, bbase, NB);
    scan3<<<(N_NODES + 255) / 256, 256, 0, stream>>>(lexcl, bbase, rowptr, cursor);
    fill_csr<<<(E_EDGES + 255) / 256, 256, 0, stream>>>(src, dst, cursor, perm);

    // ---- Weight pre-split (Wl padded to 64 cols -> 8 blocks) ----
    prep_all<<<72, 256, 0, stream>>>(W1, W2, W3, W4, Wl,
                                     W1h, W1l, W2h, W2l, W3h, W3l,
                                     W4h, W4l, Wlh, Wll);

    const int aggBlocks = (N_NODES * 64 + 255) / 256;   // one wave per node
    const int rblk = (N_NODES + 31) / 32;               // 1563 blocks, 32 rows each

    // ---- Layer 1 ----
    gather_agg_h<<<aggBlocks, 256, 0, stream>>>(xh, rowptr, perm, hFh);
    gemm_h<128, 128, 128, true, 2, true><<<rblk, 256, 0, stream>>>(hFh, W1h, W1l, b1, (float*)h1h);
    gemm_h<128, 128, 128, true, 2, true><<<rblk, 256, 0, stream>>>(h1h, W2h, W2l, b2, (float*)xh);

    // ---- Layer 2 ----
    gather_agg_h<<<aggBlocks, 256, 0, stream>>>(xh, rowptr, perm, hFh);
    gemm_h<128, 256, 256, true, 2, true><<<rblk, 256, 0, stream>>>(hFh, W3h, W3l, b3, (float*)h2h);
    gemm_h<256, 256, 256, true, 2, true><<<rblk, 256, 0, stream>>>(h2h, W4h, W4l, b4, (float*)h2bh);

    // ---- Final linear (padded to F=64) ----
    gemm_h<256, 64, 40, false, 2, false><<<rblk, 256, 0, stream>>>(h2bh, Wlh, Wll, bl, out);
}

// Round 4
// 315.055 us; speedup vs baseline: 1.2039x; 1.0779x over previous
//
#include <hip/hip_runtime.h>
#include <hip/hip_bf16.h>
#include <hip/hip_fp16.h>
#include <stdint.h>

#define N_NODES 50000
#define E_EDGES 800000
#define NBKT 196           // ceil(50000/256) buckets of 256 nodes
#define PBUF 6144          // pass-2 LDS perm buffer (records); K~4096+-64

typedef short s16x8 __attribute__((ext_vector_type(8)));
typedef _Float16 f16x8 __attribute__((ext_vector_type(8)));
typedef float f32x4 __attribute__((ext_vector_type(4)));

__device__ __forceinline__ unsigned short f2h_bits(float f) {
    return __half_as_ushort(__float2half(f));
}
__device__ __forceinline__ float h2f(unsigned short u) {
    __half h = *reinterpret_cast<const __half*>(&u);
    return __half2float(h);
}
__device__ __forceinline__ float2 h2f2(unsigned int u) {
    __half2 h = *reinterpret_cast<const __half2*>(&u);
    return __half22float2(h);
}

// ---------------- Stage 1: bucket histogram + fused x->fp16 convert -------
// Grid-stride over E (== N*128/8, so same index space converts all of x).
// LDS-binned bucket counts -> 196 global atomics per WG (not 800K scattered).
__global__ __launch_bounds__(256) void khist_conv(
    const int* __restrict__ dst, int* __restrict__ gbcnt,
    const float* __restrict__ x, unsigned short* __restrict__ xh) {
    __shared__ int bcnt[NBKT];
    int t = threadIdx.x;
    for (int i = t; i < NBKT; i += 256) bcnt[i] = 0;
    __syncthreads();
    int gid = blockIdx.x * 256 + t;
    const int STRIDE = 256 * 256;
    const float4* xv = (const float4*)x;
    for (int e = gid; e < E_EDGES; e += STRIDE) {
        atomicAdd(&bcnt[dst[e] >> 8], 1);
        float4 a = xv[(size_t)2 * e];
        float4 b = xv[(size_t)2 * e + 1];
        s16x8 h;
        h[0] = (short)f2h_bits(a.x); h[1] = (short)f2h_bits(a.y);
        h[2] = (short)f2h_bits(a.z); h[3] = (short)f2h_bits(a.w);
        h[4] = (short)f2h_bits(b.x); h[5] = (short)f2h_bits(b.y);
        h[6] = (short)f2h_bits(b.z); h[7] = (short)f2h_bits(b.w);
        *(s16x8*)(xh + (size_t)e * 8) = h;
    }
    __syncthreads();
    for (int i = t; i < NBKT; i += 256) atomicAdd(&gbcnt[i], bcnt[i]);
}

// ---------------- Stage 2: scan bucket counts -> bases + cursors ----------
__global__ void scan_bkt(const int* __restrict__ gbcnt, int* __restrict__ bscan,
                         int* __restrict__ gcur) {
    __shared__ int wsum[4];
    int t = threadIdx.x, lane = t & 63, wid = t >> 6;
    int v = (t < NBKT) ? gbcnt[t] : 0;
    int x = v;
#pragma unroll
    for (int off = 1; off < 64; off <<= 1) {
        int tt = __shfl_up(x, off);
        if (lane >= off) x += tt;
    }
    if (lane == 63) wsum[wid] = x;
    __syncthreads();
    if (t == 0) {
        int s = 0;
#pragma unroll
        for (int i = 0; i < 4; i++) { int tmp = wsum[i]; wsum[i] = s; s += tmp; }
    }
    __syncthreads();
    int excl = x - v + wsum[wid];
    if (t <= NBKT) bscan[t] = excl;    // bscan[NBKT] == E
    if (t < NBKT) gcur[t] = excl;
}

// ---------------- Stage 3: LDS multisplit into bucket-major pool ----------
// Records: src(16b) | dstLow8(<<16). Full 32-record (128B) lines flushed
// coalesced; batched cursor reservations (196 parallel atomics per window).
__global__ __launch_bounds__(256) void bin_pass(
    const int* __restrict__ src, const int* __restrict__ dst,
    int* __restrict__ gcur, unsigned int* __restrict__ pool) {
    __shared__ unsigned int lbuf[NBKT][64];
    __shared__ int lcnt[NBKT];
    __shared__ int lbase[NBKT];
    int tid = threadIdx.x;
    for (int i = tid; i < NBKT; i += 256) lcnt[i] = 0;
    __syncthreads();
    const int EPG = (E_EDGES + gridDim.x - 1) / gridDim.x;
    int e0 = blockIdx.x * EPG;
    int e1 = e0 + EPG; if (e1 > E_EDGES) e1 = E_EDGES;
    for (int wbase = e0; wbase < e1; wbase += 2048) {
        int wend = wbase + 2048; if (wend > e1) wend = e1;
        // phase A: batch-load then bin (loads issued together)
        int d8[8], s8[8], n8 = 0;
        {
            int e = wbase + tid;
#pragma unroll
            for (int k = 0; k < 8; k++, e += 256)
                if (e < wend) { d8[n8] = dst[e]; s8[n8] = src[e]; n8++; }
        }
        for (int k = 0; k < n8; k++) {
            int d = d8[k];
            unsigned int rec = (unsigned int)(s8[k] & 0xFFFF) |
                               ((unsigned int)(d & 255) << 16);
            int b = d >> 8;
            int slot = atomicAdd(&lcnt[b], 1);
            if (slot < 64) lbuf[b][slot] = rec;
            else pool[atomicAdd(&gcur[b], 1)] = rec;   // rare overflow
        }
        __syncthreads();
        // phase B1: reserve pool space for full lines (parallel atomics)
        if (tid < NBKT) {
            int c = lcnt[tid]; if (c > 64) c = 64;
            int lines = c >> 5;
            if (lines) lbase[tid] = atomicAdd(&gcur[tid], lines * 32);
        }
        __syncthreads();
        // phase B2: copy full lines coalesced; compact remainders
        {
            int wid = tid >> 6, lane = tid & 63;
            for (int b = wid * 49; b < (wid + 1) * 49; b++) {
                int c = lcnt[b]; if (c > 64) c = 64;
                int lines = c >> 5, rem = c & 31;
                for (int l = 0; l < lines; l++)
                    if (lane < 32)
                        pool[lbase[b] + l * 32 + lane] = lbuf[b][l * 32 + lane];
                if (lines && lane < rem) lbuf[b][lane] = lbuf[b][lines * 32 + lane];
                if (lane == 0) lcnt[b] = rem;
            }
        }
        __syncthreads();
    }
    // drain remainders
    if (tid < NBKT) {
        int c = lcnt[tid]; if (c > 64) c = 64;
        if (c) lbase[tid] = atomicAdd(&gcur[tid], c);
    }
    __syncthreads();
    {
        int wid = tid >> 6, lane = tid & 63;
        for (int b = wid * 49; b < (wid + 1) * 49; b++) {
            int c = lcnt[b]; if (c > 64) c = 64;
            if (lane < c) pool[lbase[b] + lane] = lbuf[b][lane];
        }
    }
}

// ---------------- Stage 4: per-bucket CSR finalize -------------------------
// One WG per bucket: node histogram + scan (-> rowptr), in-LDS reorder,
// coalesced perm segment write. All global writes sequential.
__global__ __launch_bounds__(256) void build_csr(
    const unsigned int* __restrict__ pool, const int* __restrict__ bscan,
    int* __restrict__ rowptr, unsigned short* __restrict__ perm) {
    __shared__ int ncnt[256];
    __shared__ int ncur[256];
    __shared__ int wsum[4];
    __shared__ unsigned short pbuf[PBUF];
    int b = blockIdx.x, t = threadIdx.x;
    int base = bscan[b], K = bscan[b + 1] - base;
    ncnt[t] = 0;
    __syncthreads();
    for (int i = t; i < K; i += 256)
        atomicAdd(&ncnt[(pool[base + i] >> 16) & 255], 1);
    __syncthreads();
    int lane = t & 63, wid = t >> 6;
    int v = ncnt[t], x = v;
#pragma unroll
    for (int off = 1; off < 64; off <<= 1) {
        int tt = __shfl_up(x, off);
        if (lane >= off) x += tt;
    }
    if (lane == 63) wsum[wid] = x;
    __syncthreads();
    if (t == 0) {
        int s = 0;
#pragma unroll
        for (int i = 0; i < 4; i++) { int tmp = wsum[i]; wsum[i] = s; s += tmp; }
    }
    __syncthreads();
    int excl = x - v + wsum[wid];
    int node = b * 256 + t;
    if (node <= N_NODES) rowptr[node] = base + excl;  // rowptr[N]=E falls out
    ncur[t] = excl;
    __syncthreads();
    for (int i = t; i < K; i += 256) {
        unsigned int rec = pool[base + i];
        int nl = (rec >> 16) & 255;
        int pos = atomicAdd(&ncur[nl], 1);
        if (pos < PBUF) pbuf[pos] = (unsigned short)rec;
        else perm[base + pos] = (unsigned short)rec;   // statistical never
    }
    __syncthreads();
    int KK = K < PBUF ? K : PBUF;
    for (int i = t; i < KK; i += 256) perm[base + i] = pbuf[i];
}

// ---------------- Aggregation over fp16 rows, fp16 output -----------------
__global__ __launch_bounds__(256) void gather_agg_h(
    const unsigned short* __restrict__ feat,
    const int* __restrict__ rowptr,
    const unsigned short* __restrict__ perm,
    unsigned short* __restrict__ out) {
    int node = (blockIdx.x * 256 + threadIdx.x) >> 6;
    if (node >= N_NODES) return;
    int lane = threadIdx.x & 63;
    const unsigned int* fv = (const unsigned int*)feat;
    float2 acc = h2f2(fv[(size_t)node * 64 + lane]);
    int beg = rowptr[node], end = rowptr[node + 1];
    for (int base = beg; base < end; base += 64) {
        int cnt = end - base; if (cnt > 64) cnt = 64;
        int pv = (base + lane < end) ? (int)perm[base + lane] : 0;
        int j = 0;
        for (; j + 3 < cnt; j += 4) {
            int s0 = __shfl(pv, j);
            int s1 = __shfl(pv, j + 1);
            int s2 = __shfl(pv, j + 2);
            int s3 = __shfl(pv, j + 3);
            unsigned int u0 = fv[(size_t)s0 * 64 + lane];
            unsigned int u1 = fv[(size_t)s1 * 64 + lane];
            unsigned int u2 = fv[(size_t)s2 * 64 + lane];
            unsigned int u3 = fv[(size_t)s3 * 64 + lane];
            float2 f0 = h2f2(u0), f1 = h2f2(u1), f2 = h2f2(u2), f3 = h2f2(u3);
            acc.x += (f0.x + f1.x) + (f2.x + f3.x);
            acc.y += (f0.y + f1.y) + (f2.y + f3.y);
        }
        for (; j < cnt; j++) {
            int s = __shfl(pv, j);
            float2 f = h2f2(fv[(size_t)s * 64 + lane]);
            acc.x += f.x;
            acc.y += f.y;
        }
    }
    unsigned int o = (unsigned int)f2h_bits(acc.x) | ((unsigned int)f2h_bits(acc.y) << 16);
    ((unsigned int*)out)[(size_t)node * 64 + lane] = o;
}

// ---- Weight pre-split: fp16 hi + fp16 lo (residual scaled by 1024) ----
__device__ __forceinline__ void prep_one(const float* __restrict__ W,
                                         unsigned short* __restrict__ Whi,
                                         unsigned short* __restrict__ Wlo,
                                         int K, int F, int Fpad, int i) {
    int S = K / 32, T = Fpad / 16;
    int total = T * S * 64;
    if (i >= total) return;
    int lane = i & 63;
    int s = (i >> 6) % S;
    int t = (i >> 6) / S;
    int col = t * 16 + (lane & 15);
    int k0 = s * 32 + (lane >> 4) * 8;
    s16x8 vh, vl;
#pragma unroll
    for (int j = 0; j < 8; j++) {
        float w = (col < F) ? W[(size_t)(k0 + j) * F + col] : 0.f;
        unsigned short h = f2h_bits(w);
        float r = (w - h2f(h)) * 1024.0f;
        vh[j] = (short)h;
        vl[j] = (short)f2h_bits(r);
    }
    *(s16x8*)(Whi + (size_t)i * 8) = vh;
    *(s16x8*)(Wlo + (size_t)i * 8) = vl;
}

__global__ void prep_all(const float* W1, const float* W2, const float* W3,
                         const float* W4, const float* Wl,
                         unsigned short* W1h, unsigned short* W1l,
                         unsigned short* W2h, unsigned short* W2l,
                         unsigned short* W3h, unsigned short* W3l,
                         unsigned short* W4h, unsigned short* W4l,
                         unsigned short* Wlh, unsigned short* Wll) {
    int b = blockIdx.x, t = threadIdx.x;
    if (b < 8)       prep_one(W1, W1h, W1l, 128, 128, 128, b * 256 + t);
    else if (b < 16) prep_one(W2, W2h, W2l, 128, 128, 128, (b - 8) * 256 + t);
    else if (b < 32) prep_one(W3, W3h, W3l, 128, 256, 256, (b - 16) * 256 + t);
    else if (b < 64) prep_one(W4, W4h, W4l, 256, 256, 256, (b - 32) * 256 + t);
    else             prep_one(Wl, Wlh, Wll, 256, 40, 64, (b - 64) * 256 + t);
}

// ---- GEMM, fp16 MFMA (unchanged from R3) ----
template <int K, int F, int FOUT, bool RELU, int RPW, bool HOUT>
__global__ __launch_bounds__(256) void gemm_h(
    const unsigned short* __restrict__ A,
    const unsigned short* __restrict__ Whi,
    const unsigned short* __restrict__ Wlo,
    const float* __restrict__ bias,
    float* __restrict__ out) {
    constexpr int S = K / 32;
    constexpr int T = F / 16;
    constexpr int TL = T / 4;
    int wave = threadIdx.x >> 6;
    int lane = threadIdx.x & 63;
    int row0 = blockIdx.x * (16 * RPW);
    if (row0 >= N_NODES) return;
    int lm = lane & 15;
    int quad = lane >> 4;
    bool rv[RPW];
#pragma unroll
    for (int r = 0; r < RPW; r++) rv[r] = (row0 + r * 16) < N_NODES;

    f16x8 a[RPW][S];
#pragma unroll
    for (int r = 0; r < RPW; r++) {
        int rr = rv[r] ? row0 + r * 16 : row0;
        const unsigned short* ap = A + (size_t)(rr + lm) * K + quad * 8;
#pragma unroll
        for (int s = 0; s < S; s++)
            a[r][s] = *(const f16x8*)(ap + s * 32);
    }

    f32x4 accH[TL][RPW], accL[TL][RPW];
#pragma unroll
    for (int t = 0; t < TL; t++)
#pragma unroll
        for (int r = 0; r < RPW; r++) {
            f32x4 z = {0.f, 0.f, 0.f, 0.f};
            accH[t][r] = z;
            accL[t][r] = z;
        }

#pragma unroll
    for (int s = 0; s < S; s++) {
#pragma unroll
        for (int t = 0; t < TL; t++) {
            int tg = wave * TL + t;
            const size_t fi = (size_t)((tg * S + s) * 64 + lane) * 8;
            const f16x8 bh = *(const f16x8*)(Whi + fi);
            const f16x8 bl = *(const f16x8*)(Wlo + fi);
#pragma unroll
            for (int r = 0; r < RPW; r++) {
                accH[t][r] = __builtin_amdgcn_mfma_f32_16x16x32_f16(a[r][s], bh, accH[t][r], 0, 0, 0);
                accL[t][r] = __builtin_amdgcn_mfma_f32_16x16x32_f16(a[r][s], bl, accL[t][r], 0, 0, 0);
            }
        }
    }

    const float ls = 1.0f / 1024.0f;
#pragma unroll
    for (int r = 0; r < RPW; r++) {
        if (!rv[r]) break;
        int orow = row0 + r * 16 + quad * 4;
#pragma unroll
        for (int t = 0; t < TL; t++) {
            int col = (wave * TL + t) * 16 + lm;
            if (FOUT < F && col >= FOUT) continue;
            float bv = bias[col];
#pragma unroll
            for (int q = 0; q < 4; q++) {
                float vv = fmaf(accL[t][r][q], ls, accH[t][r][q]) + bv;
                if (RELU) vv = fmaxf(vv, 0.f);
                if (HOUT) {
                    ((unsigned short*)out)[(size_t)(orow + q) * FOUT + col] = f2h_bits(vv);
                } else {
                    out[(size_t)(orow + q) * FOUT + col] = vv;
                }
            }
        }
    }
}

extern "C" void kernel_launch(void* const* d_in, const int* in_sizes, int n_in,
                              void* d_out, int out_size, void* d_ws, size_t ws_size,
                              hipStream_t stream) {
    const float* x  = (const float*)d_in[0];
    const int* ei   = (const int*)d_in[1];
    const float* W1 = (const float*)d_in[2];
    const float* b1 = (const float*)d_in[3];
    const float* W2 = (const float*)d_in[4];
    const float* b2 = (const float*)d_in[5];
    const float* W3 = (const float*)d_in[6];
    const float* b3 = (const float*)d_in[7];
    const float* W4 = (const float*)d_in[8];
    const float* b4 = (const float*)d_in[9];
    const float* Wl = (const float*)d_in[10];
    const float* bl = (const float*)d_in[11];
    float* out = (float*)d_out;

    const int* src = ei;
    const int* dst = ei + E_EDGES;

    char* ws = (char*)d_ws;
    size_t off = 0;
    // fp16 activation planes
    unsigned short* xh  = (unsigned short*)(ws + off); off += (size_t)N_NODES * 128 * 2; // x / h1b
    unsigned short* hFh = (unsigned short*)(ws + off); off += (size_t)N_NODES * 128 * 2; // agg out
    unsigned short* h1h = (unsigned short*)(ws + off); off += (size_t)N_NODES * 128 * 2;
    unsigned short* h2h = (unsigned short*)(ws + off); off += (size_t)N_NODES * 256 * 2;
    unsigned short* h2bh= (unsigned short*)(ws + off); off += (size_t)N_NODES * 256 * 2;
    // weight planes (fp16 hi / fp16 lo*1024)
    unsigned short* W1h = (unsigned short*)(ws + off); off += 16384 * 2;
    unsigned short* W1l = (unsigned short*)(ws + off); off += 16384 * 2;
    unsigned short* W2h = (unsigned short*)(ws + off); off += 16384 * 2;
    unsigned short* W2l = (unsigned short*)(ws + off); off += 16384 * 2;
    unsigned short* W3h = (unsigned short*)(ws + off); off += 32768 * 2;
    unsigned short* W3l = (unsigned short*)(ws + off); off += 32768 * 2;
    unsigned short* W4h = (unsigned short*)(ws + off); off += 65536 * 2;
    unsigned short* W4l = (unsigned short*)(ws + off); off += 65536 * 2;
    unsigned short* Wlh = (unsigned short*)(ws + off); off += 16384 * 2;
    unsigned short* Wll = (unsigned short*)(ws + off); off += 16384 * 2;
    off = (off + 255) & ~(size_t)255;
    // CSR machinery
    unsigned int* pool = (unsigned int*)(ws + off); off += (size_t)E_EDGES * 4;
    unsigned short* perm = (unsigned short*)(ws + off); off += (size_t)E_EDGES * 2;
    off = (off + 255) & ~(size_t)255;
    int* rowptr = (int*)(ws + off); off += (size_t)(N_NODES + 1) * 4;
    int* gbcnt  = (int*)(ws + off); off += 256 * 4;
    int* bscan  = (int*)(ws + off); off += 256 * 4;
    int* gcur   = (int*)(ws + off); off += 256 * 4;
    (void)ws_size; (void)in_sizes; (void)n_in; (void)out_size;

    // ---- CSR build (multisplit) + x->fp16 convert ----
    (void)hipMemsetAsync(gbcnt, 0, 256 * 4, stream);
    khist_conv<<<256, 256, 0, stream>>>(dst, gbcnt, x, xh);
    scan_bkt<<<1, 256, 0, stream>>>(gbcnt, bscan, gcur);
    bin_pass<<<256, 256, 0, stream>>>(src, dst, gcur, pool);
    build_csr<<<NBKT, 256, 0, stream>>>(pool, bscan, rowptr, perm);

    // ---- Weight pre-split ----
    prep_all<<<72, 256, 0, stream>>>(W1, W2, W3, W4, Wl,
                                     W1h, W1l, W2h, W2l, W3h, W3l,
                                     W4h, W4l, Wlh, Wll);

    const int aggBlocks = (N_NODES * 64 + 255) / 256;   // one wave per node
    const int rblk = (N_NODES + 31) / 32;               // 1563 blocks, 32 rows each

    // ---- Layer 1 ----
    gather_agg_h<<<aggBlocks, 256, 0, stream>>>(xh, rowptr, perm, hFh);
    gemm_h<128, 128, 128, true, 2, true><<<rblk, 256, 0, stream>>>(hFh, W1h, W1l, b1, (float*)h1h);
    gemm_h<128, 128, 128, true, 2, true><<<rblk, 256, 0, stream>>>(h1h, W2h, W2l, b2, (float*)xh);

    // ---- Layer 2 ----
    gather_agg_h<<<aggBlocks, 256, 0, stream>>>(xh, rowptr, perm, hFh);
    gemm_h<128, 256, 256, true, 2, true><<<rblk, 256, 0, stream>>>(hFh, W3h, W3l, b3, (float*)h2h);
    gemm_h<256, 256, 256, true, 2, true><<<rblk, 256, 0, stream>>>(h2h, W4h, W4l, b4, (float*)h2bh);

    // ---- Final linear (padded to F=64) ----
    gemm_h<256, 64, 40, false, 2, false><<<rblk, 256, 0, stream>>>(h2bh, Wlh, Wll, bl, out);
}